// Round 4
// baseline (288.026 us; speedup 1.0000x reference)
//
#include <hip/hip_runtime.h>
#include <hip/hip_bf16.h>
#include <math.h>

typedef unsigned short u16;

#define BATCH 16384
#define HID   512
#define KDIM  1024   // INPUT + HIDDEN
#define BM    256    // batch rows per block (2 wave-rows of 128)
#define NSTEP 16     // K-steps of 64

typedef __bf16 bf16x8 __attribute__((ext_vector_type(8)));
typedef float  floatx4 __attribute__((ext_vector_type(4)));

__device__ __forceinline__ float fast_sigmoid(float x) {
  return 1.0f / (1.0f + __expf(-x));
}
__device__ __forceinline__ float fast_tanh(float x) {
  float e = __expf(-2.0f * fabsf(x));
  float t = (1.0f - e) / (1.0f + e);
  return x >= 0.0f ? t : -t;
}
__device__ __forceinline__ u16 f2bf(float f) {
  return __builtin_bit_cast(u16, __float2bfloat16(f));
}

// ---------- pre-pass: W only ----------
// Wf: MFMA-FRAGMENT-MAJOR weights so B-loads are one coalesced dwordx4:
//   elem (gate g, per-gate col n, k) at
//   (((g*32 + n/16)*32 + k/32)*64 + ((k>>3)&3)*16 + (n&15))*8 + (k&7)
__global__ __launch_bounds__(256) void pack_w_kernel(
    const float* __restrict__ Wi, const float* __restrict__ Wf_,
    const float* __restrict__ Wo, const float* __restrict__ Wg,
    u16* __restrict__ Wf) {
  int grow = blockIdx.x;                  // 0..2047, order [Wi|Wf|Wo|Wg]
  int k = threadIdx.x * 4;
  int g = grow >> 9;
  int n = grow & (HID - 1);
  const float* s = g == 0 ? Wi : g == 1 ? Wf_ : g == 2 ? Wo : Wg;
  float4 v = *(const float4*)(s + (size_t)n * KDIM + k);
  ushort4 o;
  o.x = f2bf(v.x); o.y = f2bf(v.y); o.z = f2bf(v.z); o.w = f2bf(v.w);
  size_t d = ((size_t)((g * 32 + (n >> 4)) * 32 + (k >> 5)) * 64 +
              ((k >> 3) & 3) * 16 + (n & 15)) * 8 + (k & 7);
  *(ushort4*)(Wf + d) = o;
}

// ---------- main fused GEMM + LSTM epilogue, 8-phase-style schedule ----------
// Tile: BM=256 x 256 gate-cols (4 gates x 64). 8 waves = 2 m-halves x 4
// n-quarters; per-wave output 128 rows x 16 cols/gate (same MFMA work/wave
// as R1). W stays in REGISTERS (L2-resident, fragment-major). X is
// reg-staged fp32->bf16 with R1's verified zero-conflict pattern: LDS write
// address LINEAR in lane, swizzle applied to the GLOBAL source chunk
// (c = (lane&7)^(row&7)); compute reads chunk (kq)^(row&7) -- unchanged.
// Per K-step s, 4 phases (T3), each: {4x ds_read a ; stage slice ; barrier ;
// lgkmcnt(0) ; setprio ; 16 MFMA ; setprio ; barrier}. Staging for s+1:
// loads issued P0/P1, cvt+ds_write P2/P3 under counted vmcnt (T4; VMEM
// retires in order, so counting only the newer X loads is safe even with
// compiler-managed B loads, which are strictly older). loadB(s+1) at P3
// tail, after b's last use.
__global__ __launch_bounds__(512, 2) void lstm_gemm_kernel(
    const float* __restrict__ input_, const float* __restrict__ prev_h,
    const u16* __restrict__ Wf,
    const float* __restrict__ Bi, const float* __restrict__ Bf,
    const float* __restrict__ Bo, const float* __restrict__ Bg,
    const float* __restrict__ prevC, float* __restrict__ out) {
  __shared__ u16 lbf[2][16384];   // 2 x 256 rows x 64 elems bf16 = 64 KB

  const int tid = threadIdx.x;
  const int wave = tid >> 6, lane = tid & 63;
  const int lrow = lane & 15, lquad = lane >> 4;
  const int wr = wave >> 2, wc = wave & 3;

  // XCD-aware swizzle (T1): hw dispatch id -> logical id so that the 8
  // sibling n-blocks of one m-slab land on ONE XCD (share X rows in L2).
  // 512 blocks, 512%8==0 -> bijective.
  int hw = (int)(blockIdx.x + gridDim.x * blockIdx.y);
  int lid = (hw & 7) * 64 + (hw >> 3);
  const int m_block = (lid >> 3) * BM;
  const int ntg = (lid & 7) * 4 + wc;      // global 16-col tile id, 0..31

  // staging geometry: wave stages rows [wave*32, wave*32+32); instr i
  // (0..3) covers rows i*8 + (lane>>3); lane fetches logical chunk
  // c = (lane&7)^(row&7) (8 floats) and writes it lane-linear.
  const int srow = lane >> 3;                       // row&7
  const int schunk = (lane & 7) ^ srow;             // logical chunk
  int i_off[4];
#pragma unroll
  for (int i = 0; i < 4; ++i)
    i_off[i] = (m_block + wave * 32 + i * 8 + srow) * HID + schunk * 8;
  const int lw_off = wave * 2048 + lane * 8;        // + i*512, elems

  floatx4 acc[4][8];   // [gate][m-tile] (AGPRs)
#pragma unroll
  for (int g = 0; g < 4; ++g)
#pragma unroll
    for (int mt = 0; mt < 8; ++mt)
      acc[g][mt] = (floatx4){0.f, 0.f, 0.f, 0.f};

  float4 r[4][2];      // in-flight fp32 X for next step (32 VGPRs)
  auto ldXi = [&](int t, int i) {
    const float* bse = ((t < 8) ? prev_h : input_) + i_off[i] + (t & 7) * 64;
    r[i][0] = *(const float4*)bse;
    r[i][1] = *(const float4*)(bse + 4);
  };
  auto cwi = [&](u16* LW, int i) {
    union { u16 u[8]; bf16x8 v; } t;
    t.u[0] = f2bf(r[i][0].x); t.u[1] = f2bf(r[i][0].y);
    t.u[2] = f2bf(r[i][0].z); t.u[3] = f2bf(r[i][0].w);
    t.u[4] = f2bf(r[i][1].x); t.u[5] = f2bf(r[i][1].y);
    t.u[6] = f2bf(r[i][1].z); t.u[7] = f2bf(r[i][1].w);
    *(bf16x8*)&LW[lw_off + i * 512] = t.v;   // linear-in-lane, conflict-free
  };

  bf16x8 b[2][4];      // single B buffer (32 VGPRs)
  auto loadB = [&](int S) {
#pragma unroll
    for (int kk = 0; kk < 2; ++kk)
#pragma unroll
      for (int g = 0; g < 4; ++g)
        b[kk][g] = *(const bf16x8*)(
            Wf + (((size_t)(g * 32 + ntg) * 32 + (S * 2 + kk)) << 9) +
            lane * 8);
  };

  auto rdA = [&](const u16* LA, int kk, int mt) {
    return *(const bf16x8*)
        &LA[(wr * 128 + mt * 16 + lrow) * 64 +
            (((kk * 4 + lquad) ^ (lrow & 7)) * 8)];
  };
  auto cluster = [&](bf16x8 a0, bf16x8 a1, bf16x8 a2, bf16x8 a3,
                     int kk, int mtb) {
    __builtin_amdgcn_s_setprio(1);
#pragma unroll
    for (int g = 0; g < 4; ++g) {
      acc[g][mtb + 0] = __builtin_amdgcn_mfma_f32_16x16x32_bf16(
          a0, b[kk][g], acc[g][mtb + 0], 0, 0, 0);
      acc[g][mtb + 1] = __builtin_amdgcn_mfma_f32_16x16x32_bf16(
          a1, b[kk][g], acc[g][mtb + 1], 0, 0, 0);
      acc[g][mtb + 2] = __builtin_amdgcn_mfma_f32_16x16x32_bf16(
          a2, b[kk][g], acc[g][mtb + 2], 0, 0, 0);
      acc[g][mtb + 3] = __builtin_amdgcn_mfma_f32_16x16x32_bf16(
          a3, b[kk][g], acc[g][mtb + 3], 0, 0, 0);
    }
    __builtin_amdgcn_s_setprio(0);
  };

  // ---- prologue: stage step 0, load B(0) ----
  ldXi(0, 0); ldXi(0, 1); ldXi(0, 2); ldXi(0, 3);
  asm volatile("" ::: "memory");          // keep X issue-order before B
  loadB(0);
  asm volatile("s_waitcnt vmcnt(8)" ::: "memory");   // X(0) landed; B newer
  __builtin_amdgcn_sched_barrier(0);
  {
    u16* LW = &lbf[0][0];
    cwi(LW, 0); cwi(LW, 1); cwi(LW, 2); cwi(LW, 3);
  }
  asm volatile("s_waitcnt lgkmcnt(0)" ::: "memory");
  __builtin_amdgcn_s_barrier();

  // ---- main loop: 4 phases per K-step ----
#pragma unroll 2
  for (int s = 0; s < NSTEP; ++s) {
    const u16* LA = &lbf[s & 1][0];
    u16* LW = &lbf[(s & 1) ^ 1][0];
    const bool st = (s + 1 < NSTEP);
    bf16x8 a0, a1, a2, a3;

    // P0: kk=0, mt0-3 | issue X(s+1) slices 0,1
    a0 = rdA(LA, 0, 0); a1 = rdA(LA, 0, 1);
    a2 = rdA(LA, 0, 2); a3 = rdA(LA, 0, 3);
    if (st) { ldXi(s + 1, 0); ldXi(s + 1, 1); }
    __builtin_amdgcn_s_barrier();
    asm volatile("s_waitcnt lgkmcnt(0)" ::: "memory");
    __builtin_amdgcn_sched_barrier(0);
    cluster(a0, a1, a2, a3, 0, 0);
    __builtin_amdgcn_s_barrier();

    // P1: kk=0, mt4-7 | issue X(s+1) slices 2,3
    a0 = rdA(LA, 0, 4); a1 = rdA(LA, 0, 5);
    a2 = rdA(LA, 0, 6); a3 = rdA(LA, 0, 7);
    if (st) { ldXi(s + 1, 2); ldXi(s + 1, 3); }
    __builtin_amdgcn_s_barrier();
    asm volatile("s_waitcnt lgkmcnt(0)" ::: "memory");
    __builtin_amdgcn_sched_barrier(0);
    cluster(a0, a1, a2, a3, 0, 4);
    __builtin_amdgcn_s_barrier();

    // P2: kk=1, mt0-3 | cvt+write slices 0,1 (vmcnt(4): slices 2,3 newer)
    a0 = rdA(LA, 1, 0); a1 = rdA(LA, 1, 1);
    a2 = rdA(LA, 1, 2); a3 = rdA(LA, 1, 3);
    if (st) {
      asm volatile("s_waitcnt vmcnt(4)" ::: "memory");
      __builtin_amdgcn_sched_barrier(0);
      cwi(LW, 0); cwi(LW, 1);
    }
    __builtin_amdgcn_s_barrier();
    asm volatile("s_waitcnt lgkmcnt(0)" ::: "memory");
    __builtin_amdgcn_sched_barrier(0);
    cluster(a0, a1, a2, a3, 1, 0);
    __builtin_amdgcn_s_barrier();

    // P3: kk=1, mt4-7 | cvt+write slices 2,3 ; loadB(s+1) after b last use
    a0 = rdA(LA, 1, 4); a1 = rdA(LA, 1, 5);
    a2 = rdA(LA, 1, 6); a3 = rdA(LA, 1, 7);
    if (st) {
      asm volatile("s_waitcnt vmcnt(0)" ::: "memory");  // only X 2,3 pending
      __builtin_amdgcn_sched_barrier(0);
      cwi(LW, 2); cwi(LW, 3);
    }
    __builtin_amdgcn_s_barrier();
    asm volatile("s_waitcnt lgkmcnt(0)" ::: "memory");
    __builtin_amdgcn_sched_barrier(0);
    cluster(a0, a1, a2, a3, 1, 4);
    if (st) loadB(s + 1);               // in flight across the barrier
    __builtin_amdgcn_s_barrier();
  }

  // ---- epilogue. C layout (verified): col=lane&15, row=lquad*4+reg ----
  const int j = ntg * 16 + lrow;        // 0..511
  const float vbi = Bi[j], vbf = Bf[j], vbo = Bo[j], vbg = Bg[j];
  float* outH = out;
  float* outC = out + (size_t)BATCH * HID;
#pragma unroll
  for (int mt = 0; mt < 8; ++mt) {
    int rowb = m_block + wr * 128 + mt * 16 + lquad * 4;
#pragma unroll
    for (int rg = 0; rg < 4; ++rg) {
      int row = rowb + rg;
      float gi = fast_sigmoid(acc[0][mt][rg] + vbi);
      float gf = fast_sigmoid(acc[1][mt][rg] + vbf);
      float go = fast_sigmoid(acc[2][mt][rg] + vbo);
      float gg = fast_tanh(acc[3][mt][rg] + vbg);
      float c = gf * prevC[row * HID + j] + gi * gg;
      float h = fast_tanh(c) * go;
      outH[row * HID + j] = h;
      outC[row * HID + j] = c;
    }
  }
}

// ---------- slow fallback if ws too small (correctness insurance) ----------
__global__ void lstm_fallback_kernel(
    const float* __restrict__ input_, const float* __restrict__ prev_h,
    const float* __restrict__ prevC,
    const float* __restrict__ Wi, const float* __restrict__ Bi,
    const float* __restrict__ Wf, const float* __restrict__ Bf,
    const float* __restrict__ Wo, const float* __restrict__ Bo,
    const float* __restrict__ Wg, const float* __restrict__ Bg,
    float* __restrict__ out) {
  int idx = blockIdx.x * blockDim.x + threadIdx.x;
  int b = idx / HID, j = idx % HID;
  if (b >= BATCH) return;
  float si = 0.f, sf = 0.f, so = 0.f, sg = 0.f;
  for (int k = 0; k < KDIM; ++k) {
    float x = (k < HID) ? prev_h[b * HID + k] : input_[b * HID + (k - HID)];
    si += x * Wi[j * KDIM + k];
    sf += x * Wf[j * KDIM + k];
    so += x * Wo[j * KDIM + k];
    sg += x * Wg[j * KDIM + k];
  }
  float gi = fast_sigmoid(si + Bi[j]);
  float gf = fast_sigmoid(sf + Bf[j]);
  float go = fast_sigmoid(so + Bo[j]);
  float gg = fast_tanh(sg + Bg[j]);
  float c = gf * prevC[b * HID + j] + gi * gg;
  out[b * HID + j] = fast_tanh(c) * go;
  out[(size_t)BATCH * HID + b * HID + j] = c;
}

extern "C" void kernel_launch(void* const* d_in, const int* in_sizes, int n_in,
                              void* d_out, int out_size, void* d_ws, size_t ws_size,
                              hipStream_t stream) {
  const float* input_ = (const float*)d_in[0];
  const float* prev_h = (const float*)d_in[1];
  const float* prev_c = (const float*)d_in[2];
  const float* W_i = (const float*)d_in[3];
  const float* b_i = (const float*)d_in[4];
  const float* W_f = (const float*)d_in[5];
  const float* b_f = (const float*)d_in[6];
  const float* W_g = (const float*)d_in[7];
  const float* b_g = (const float*)d_in[8];
  const float* W_o = (const float*)d_in[9];
  const float* b_o = (const float*)d_in[10];
  float* out = (float*)d_out;

  const size_t ws_needed = (size_t)4 * HID * KDIM * sizeof(u16);   // 4 MB

  if (ws_size < ws_needed) {
    int total = BATCH * HID;
    lstm_fallback_kernel<<<(total + 255) / 256, 256, 0, stream>>>(
        input_, prev_h, prev_c, W_i, b_i, W_f, b_f, W_o, b_o, W_g, b_g, out);
    return;
  }

  u16* Wfp = (u16*)d_ws;                      // fragment-major bf16 W, 4 MB

  pack_w_kernel<<<4 * HID, 256, 0, stream>>>(W_i, W_f, W_o, W_g, Wfp);

  dim3 grid(8, BATCH / BM);                   // 8 n-blocks x 64 m-blocks
  lstm_gemm_kernel<<<grid, 512, 0, stream>>>(input_, prev_h, Wfp,
                                             b_i, b_f, b_o, b_g, prev_c, out);
}